// Round 1
// baseline (400.027 us; speedup 1.0000x reference)
//
#include <hip/hip_runtime.h>

#define T_REL   4
#define E_EDGES 131072
#define N_NODES 4096
#define C_CH    2
#define HOUT    64

// ---------------------------------------------------------------- CSR build
__global__ void count_kernel(const int* __restrict__ ei, int* __restrict__ counts) {
    int idx = blockIdx.x * blockDim.x + threadIdx.x;
    if (idx >= T_REL * E_EDGES) return;
    int t = idx >> 17;              // E = 2^17
    int e = idx & (E_EDGES - 1);
    int src = ei[(t * 2 + 0) * E_EDGES + e];
    atomicAdd(&counts[src], 1);
}

__global__ void scan_kernel(const int* __restrict__ counts,
                            int* __restrict__ row_start,
                            int* __restrict__ cursor) {
    __shared__ int sdata[1024];
    int tid = threadIdx.x;          // 1024 threads, 4 elements each
    int base = tid * 4;
    int v[4];
    int s = 0;
#pragma unroll
    for (int j = 0; j < 4; ++j) { v[j] = counts[base + j]; s += v[j]; }
    sdata[tid] = s;
    __syncthreads();
    for (int off = 1; off < 1024; off <<= 1) {
        int x = sdata[tid] + ((tid >= off) ? sdata[tid - off] : 0);
        __syncthreads();
        sdata[tid] = x;
        __syncthreads();
    }
    int run = sdata[tid] - s;       // exclusive prefix
#pragma unroll
    for (int j = 0; j < 4; ++j) {
        row_start[base + j] = run;
        cursor[base + j]    = run;
        run += v[j];
    }
    if (tid == 1023) row_start[4096] = run;
}

__global__ void scatter_kernel(const int* __restrict__ ei,
                               const float* __restrict__ ew,
                               int* __restrict__ cursor,
                               unsigned* __restrict__ colt,
                               float* __restrict__ wv) {
    int idx = blockIdx.x * blockDim.x + threadIdx.x;
    if (idx >= T_REL * E_EDGES) return;
    int t = idx >> 17;
    int e = idx & (E_EDGES - 1);
    int src = ei[(t * 2 + 0) * E_EDGES + e];
    int dst = ei[(t * 2 + 1) * E_EDGES + e];
    float w = ew[t * E_EDGES + e];
    int pos = atomicAdd(&cursor[src], 1);
    colt[pos] = (unsigned)dst | ((unsigned)t << 16);
    wv[pos] = w;
}

// ------------------------------------------------- H0[c,n,h] = X[n,:] @ Ws[c,:,h]
__global__ void init_kernel(const float* __restrict__ X,
                            const float* __restrict__ Ws,
                            float* __restrict__ H0, int K) {
    int idx = blockIdx.x * blockDim.x + threadIdx.x;   // c*N*64 + n*64 + h
    int h = idx & 63;
    int n = (idx >> 6) & (N_NODES - 1);
    int c = idx >> 18;
    const float* x = X + n * K;
    const float* w = Ws + (c * K) * HOUT + h;
    float acc = 0.f;
    for (int k = 0; k < K; ++k) acc += x[k] * w[k * HOUT];
    H0[idx] = acc;
}

// -------- Hout[c,i,:] = sum_{e in row i} softmax(conv_w[l,c,:])[t_e]*w_e * Hin[c,dst_e,:]
__global__ void spmm_kernel(const int* __restrict__ row_start,
                            const unsigned* __restrict__ colt,
                            const float* __restrict__ wv,
                            const float* __restrict__ Hin,
                            float* __restrict__ Hout,
                            const float* __restrict__ conv_w, int layer) {
    int row  = blockIdx.x;
    int c    = blockIdx.y;
    int lane = threadIdx.x;          // 64 lanes = h
    // softmax over T (tiny, per-thread)
    float f[T_REL];
    float m = -1e30f;
#pragma unroll
    for (int t = 0; t < T_REL; ++t) {
        f[t] = conv_w[(layer * C_CH + c) * T_REL + t];
        m = fmaxf(m, f[t]);
    }
    float s = 0.f;
#pragma unroll
    for (int t = 0; t < T_REL; ++t) { f[t] = expf(f[t] - m); s += f[t]; }
    float inv = 1.0f / s;
#pragma unroll
    for (int t = 0; t < T_REL; ++t) f[t] *= inv;

    const float* Hc = Hin + c * (N_NODES * HOUT);
    int e0 = row_start[row], e1 = row_start[row + 1];
    float acc = 0.f;
    for (int e = e0; e < e1; ++e) {
        unsigned p = colt[e];
        int dst = p & 0xFFFF;
        int t   = p >> 16;
        float w = wv[e] * f[t];
        acc += w * Hc[dst * HOUT + lane];
    }
    Hout[(c * N_NODES + row) * HOUT + lane] = acc;
}

// ------- out[n,h] = relu( sum_j relu(0.1*H0 + 0.9*H2)[n,j] * lin_w[j,h] + lin_b[h] )
__global__ void combine_kernel(const float* __restrict__ H0,
                               const float* __restrict__ H2,
                               const float* __restrict__ lin_w,
                               const float* __restrict__ lin_b,
                               float* __restrict__ out) {
    int n = blockIdx.x;
    int h = threadIdx.x;             // 64
    float acc = lin_b[h];
#pragma unroll 4
    for (int j = 0; j < C_CH * HOUT; ++j) {
        int c = j >> 6, hh = j & 63;
        int off = (c * N_NODES + n) * HOUT + hh;
        float hv = 0.1f * H0[off] + 0.9f * H2[off];
        hv = fmaxf(hv, 0.f);
        acc += hv * lin_w[j * HOUT + h];
    }
    out[n * HOUT + h] = fmaxf(acc, 0.f);
}

extern "C" void kernel_launch(void* const* d_in, const int* in_sizes, int n_in,
                              void* d_out, int out_size, void* d_ws, size_t ws_size,
                              hipStream_t stream) {
    const int*   ei  = (const int*)d_in[0];
    const float* ew  = (const float*)d_in[1];
    const float* X   = (const float*)d_in[2];
    const float* Ws1 = (const float*)d_in[3];
    const float* cw1 = (const float*)d_in[4];
    const float* lw1 = (const float*)d_in[5];
    const float* lb1 = (const float*)d_in[6];
    const float* Ws2 = (const float*)d_in[7];
    const float* cw2 = (const float*)d_in[8];
    const float* lw2 = (const float*)d_in[9];
    const float* lb2 = (const float*)d_in[10];
    float* out = (float*)d_out;

    char* ws = (char*)d_ws;
    size_t off = 0;
    auto alloc = [&](size_t bytes) -> void* {
        void* p = ws + off;
        off += (bytes + 255) & ~size_t(255);
        return p;
    };
    int*      counts    = (int*)alloc(N_NODES * 4);
    int*      row_start = (int*)alloc((N_NODES + 1) * 4);
    int*      cursor    = (int*)alloc(N_NODES * 4);
    unsigned* colt      = (unsigned*)alloc((size_t)T_REL * E_EDGES * 4);
    float*    wv        = (float*)alloc((size_t)T_REL * E_EDGES * 4);
    float*    H0        = (float*)alloc((size_t)C_CH * N_NODES * HOUT * 4);
    float*    Ha        = (float*)alloc((size_t)C_CH * N_NODES * HOUT * 4);
    float*    Hb        = (float*)alloc((size_t)C_CH * N_NODES * HOUT * 4);
    float*    mid       = (float*)alloc((size_t)N_NODES * HOUT * 4);

    hipMemsetAsync(counts, 0, N_NODES * 4, stream);

    int nEdgeThreads = T_REL * E_EDGES;
    count_kernel<<<nEdgeThreads / 256, 256, 0, stream>>>(ei, counts);
    scan_kernel<<<1, 1024, 0, stream>>>(counts, row_start, cursor);
    scatter_kernel<<<nEdgeThreads / 256, 256, 0, stream>>>(ei, ew, cursor, colt, wv);

    dim3 gspmm(N_NODES, C_CH);
    int initBlocks = (C_CH * N_NODES * HOUT) / 256;

    // FastGTN #1 (w_in = 128)
    init_kernel<<<initBlocks, 256, 0, stream>>>(X, Ws1, H0, 128);
    spmm_kernel<<<gspmm, 64, 0, stream>>>(row_start, colt, wv, H0, Ha, cw1, 0);
    spmm_kernel<<<gspmm, 64, 0, stream>>>(row_start, colt, wv, Ha, Hb, cw1, 1);
    combine_kernel<<<N_NODES, 64, 0, stream>>>(H0, Hb, lw1, lb1, mid);

    // FastGTN #2 (w_in = 64)
    init_kernel<<<initBlocks, 256, 0, stream>>>(mid, Ws2, H0, 64);
    spmm_kernel<<<gspmm, 64, 0, stream>>>(row_start, colt, wv, H0, Ha, cw2, 0);
    spmm_kernel<<<gspmm, 64, 0, stream>>>(row_start, colt, wv, Ha, Hb, cw2, 1);
    combine_kernel<<<N_NODES, 64, 0, stream>>>(H0, Hb, lw2, lb2, out);
}

// Round 2
// 200.462 us; speedup vs baseline: 1.9955x; 1.9955x over previous
//
#include <hip/hip_runtime.h>

#define T_REL   4
#define E_EDGES 131072
#define N_NODES 4096
#define C_CH    2
#define HOUT    64
#define NE_TOT  (T_REL * E_EDGES)

// ---------------------------------------------------------------- CSR build
__global__ void count_kernel(const int* __restrict__ ei, int* __restrict__ counts) {
    int idx = blockIdx.x * blockDim.x + threadIdx.x;
    int t = idx >> 17;              // E = 2^17
    int e = idx & (E_EDGES - 1);
    int src = ei[(t * 2 + 0) * E_EDGES + e];
    atomicAdd(&counts[src], 1);
}

__global__ void scan_kernel(const int* __restrict__ counts,
                            int* __restrict__ row_start,
                            int* __restrict__ cursor) {
    __shared__ int sdata[1024];
    int tid = threadIdx.x;          // 1024 threads, 4 elements each
    int base = tid * 4;
    int v[4];
    int s = 0;
#pragma unroll
    for (int j = 0; j < 4; ++j) { v[j] = counts[base + j]; s += v[j]; }
    sdata[tid] = s;
    __syncthreads();
    for (int off = 1; off < 1024; off <<= 1) {
        int x = sdata[tid] + ((tid >= off) ? sdata[tid - off] : 0);
        __syncthreads();
        sdata[tid] = x;
        __syncthreads();
    }
    int run = sdata[tid] - s;       // exclusive prefix
#pragma unroll
    for (int j = 0; j < 4; ++j) {
        row_start[base + j] = run;
        cursor[base + j]    = run;
        run += v[j];
    }
    if (tid == 1023) row_start[4096] = run;
}

__global__ void scatter_kernel(const int* __restrict__ ei,
                               const float* __restrict__ ew,
                               int* __restrict__ cursor,
                               uint2* __restrict__ edges) {
    int idx = blockIdx.x * blockDim.x + threadIdx.x;
    int t = idx >> 17;
    int e = idx & (E_EDGES - 1);
    int src = ei[(t * 2 + 0) * E_EDGES + e];
    int dst = ei[(t * 2 + 1) * E_EDGES + e];
    float w = ew[t * E_EDGES + e];
    int pos = atomicAdd(&cursor[src], 1);
    edges[pos] = make_uint2((unsigned)dst | ((unsigned)t << 16), __float_as_uint(w));
}

// ------------------------------------------------- H0[c,n,h] = X[n,:] @ Ws1[c,:,h]
__global__ void init_kernel(const float* __restrict__ X,
                            const float* __restrict__ Ws,
                            float* __restrict__ H0) {
    int idx = blockIdx.x * 256 + threadIdx.x;   // c*N*64 + n*64 + h
    int h = idx & 63;
    int n = (idx >> 6) & (N_NODES - 1);
    int c = idx >> 18;
    const float4* xv = (const float4*)(X + n * 128);
    const float*  w  = Ws + c * 128 * HOUT + h;
    float acc = 0.f;
#pragma unroll 8
    for (int k4 = 0; k4 < 32; ++k4) {
        float4 xx = xv[k4];
        acc += xx.x * w[(k4 * 4 + 0) * HOUT];
        acc += xx.y * w[(k4 * 4 + 1) * HOUT];
        acc += xx.z * w[(k4 * 4 + 2) * HOUT];
        acc += xx.w * w[(k4 * 4 + 3) * HOUT];
    }
    H0[idx] = acc;
}

// ---------------------------------------------------------------- helpers
__device__ __forceinline__ void softmax4(const float* __restrict__ conv_w,
                                         int layer, int c, float f[4]) {
#pragma unroll
    for (int t = 0; t < 4; ++t) f[t] = conv_w[(layer * C_CH + c) * T_REL + t];
    float m = fmaxf(fmaxf(f[0], f[1]), fmaxf(f[2], f[3]));
    float s = 0.f;
#pragma unroll
    for (int t = 0; t < 4; ++t) { f[t] = expf(f[t] - m); s += f[t]; }
    float inv = 1.0f / s;
#pragma unroll
    for (int t = 0; t < 4; ++t) f[t] *= inv;
}

__device__ __forceinline__ float selw(const float f[4], int t) {
    float a = (t & 1) ? f[1] : f[0];
    float b = (t & 1) ? f[3] : f[2];
    return (t & 2) ? b : a;
}

// wave-level SpMM for one (row, channel): 4 edges per step (one per 16-lane
// group), each lane gathers a float4 quarter-row; 2x unrolled; shfl reduce.
__device__ __forceinline__ float4 spmm_row(const int* __restrict__ row_start,
                                           const uint2* __restrict__ edges,
                                           const float* __restrict__ Hc,
                                           const float f[4], int row, int lane) {
    int g  = lane >> 4;    // which edge of the group of 4
    int hq = lane & 15;    // float4 slot within the 64-wide row
    int e0 = row_start[row], e1 = row_start[row + 1];
    float4 acc = make_float4(0.f, 0.f, 0.f, 0.f);
    int e = e0;
    for (; e + 8 <= e1; e += 8) {
        uint2 r0 = edges[e + g];
        uint2 r1 = edges[e + 4 + g];
        int   d0 = r0.x & 0xFFFF, t0 = (int)(r0.x >> 16);
        int   d1 = r1.x & 0xFFFF, t1 = (int)(r1.x >> 16);
        float w0 = __uint_as_float(r0.y) * selw(f, t0);
        float w1 = __uint_as_float(r1.y) * selw(f, t1);
        float4 v0 = ((const float4*)(Hc + d0 * HOUT))[hq];
        float4 v1 = ((const float4*)(Hc + d1 * HOUT))[hq];
        acc.x += w0 * v0.x; acc.y += w0 * v0.y; acc.z += w0 * v0.z; acc.w += w0 * v0.w;
        acc.x += w1 * v1.x; acc.y += w1 * v1.y; acc.z += w1 * v1.z; acc.w += w1 * v1.w;
    }
    for (; e + 4 <= e1; e += 4) {
        uint2 r0 = edges[e + g];
        int   d0 = r0.x & 0xFFFF, t0 = (int)(r0.x >> 16);
        float w0 = __uint_as_float(r0.y) * selw(f, t0);
        float4 v0 = ((const float4*)(Hc + d0 * HOUT))[hq];
        acc.x += w0 * v0.x; acc.y += w0 * v0.y; acc.z += w0 * v0.z; acc.w += w0 * v0.w;
    }
    int rem = e1 - e;
    if (g < rem) {
        uint2 r0 = edges[e + g];
        int   d0 = r0.x & 0xFFFF, t0 = (int)(r0.x >> 16);
        float w0 = __uint_as_float(r0.y) * selw(f, t0);
        float4 v0 = ((const float4*)(Hc + d0 * HOUT))[hq];
        acc.x += w0 * v0.x; acc.y += w0 * v0.y; acc.z += w0 * v0.z; acc.w += w0 * v0.w;
    }
    // combine the 4 edge-groups: after xor16+xor32 every lane has the full sum
    acc.x += __shfl_xor(acc.x, 16); acc.y += __shfl_xor(acc.y, 16);
    acc.z += __shfl_xor(acc.z, 16); acc.w += __shfl_xor(acc.w, 16);
    acc.x += __shfl_xor(acc.x, 32); acc.y += __shfl_xor(acc.y, 32);
    acc.z += __shfl_xor(acc.z, 32); acc.w += __shfl_xor(acc.w, 32);
    return acc;
}

// ---------------------------------------------------------------- layer-0 SpMM
__global__ void spmm_kernel(const int* __restrict__ row_start,
                            const uint2* __restrict__ edges,
                            const float* __restrict__ Hin,
                            float* __restrict__ Hout,
                            const float* __restrict__ conv_w) {
    int wid  = threadIdx.x >> 6;              // 4 waves: 2 rows x 2 channels
    int lane = threadIdx.x & 63;
    int row  = blockIdx.x * 2 + (wid >> 1);
    int c    = wid & 1;
    float f[4]; softmax4(conv_w, 0, c, f);
    const float* Hc = Hin + c * (N_NODES * HOUT);
    float4 acc = spmm_row(row_start, edges, Hc, f, row, lane);
    if (lane < 16)
        ((float4*)(Hout + (c * N_NODES + row) * HOUT))[lane] = acc;
}

// ------------- layer-1 SpMM + beta-combine + linear (+ next-FastGTN init)
template <bool FINAL>
__global__ void fused_tail_kernel(const int* __restrict__ row_start,
                                  const uint2* __restrict__ edges,
                                  const float* __restrict__ Hin,   // layer-1 result
                                  const float* __restrict__ H0,    // X_ (detached init)
                                  const float* __restrict__ conv_w,
                                  const float* __restrict__ lin_w,
                                  const float* __restrict__ lin_b,
                                  const float* __restrict__ Ws_next,
                                  float* __restrict__ outp) {
    __shared__ float h2s[C_CH * HOUT];
    __shared__ float hcomb[C_CH * HOUT];
    __shared__ float mids[HOUT];
    int tid  = threadIdx.x;        // 128 = 2 waves, wave == channel
    int c    = tid >> 6;
    int lane = tid & 63;
    int row  = blockIdx.x;

    float f[4]; softmax4(conv_w, 1, c, f);
    const float* Hc = Hin + c * (N_NODES * HOUT);
    float4 acc = spmm_row(row_start, edges, Hc, f, row, lane);
    if (lane < 16) ((float4*)(h2s + c * HOUT))[lane] = acc;
    __syncthreads();

    // H_ = relu(0.1*X_ + 0.9*H2), laid out j = c*64 + h
    {
        float h0v = H0[(c * N_NODES + row) * HOUT + lane];
        hcomb[tid] = fmaxf(0.1f * h0v + 0.9f * h2s[tid], 0.f);
    }
    __syncthreads();

    if (FINAL) {
        if (tid < 64) {
            float a = lin_b[tid];
#pragma unroll 8
            for (int j = 0; j < C_CH * HOUT; ++j) a += hcomb[j] * lin_w[j * HOUT + tid];
            outp[row * HOUT + tid] = fmaxf(a, 0.f);
        }
    } else {
        if (tid < 64) {
            float a = lin_b[tid];
#pragma unroll 8
            for (int j = 0; j < C_CH * HOUT; ++j) a += hcomb[j] * lin_w[j * HOUT + tid];
            mids[tid] = fmaxf(a, 0.f);
        }
        __syncthreads();
        // next FastGTN init: H0'[c,row,h] = sum_k mid[k] * Ws_next[c,k,h]
        float a = 0.f;
        const float* w = Ws_next + c * HOUT * HOUT + lane;
#pragma unroll 8
        for (int k = 0; k < HOUT; ++k) a += mids[k] * w[k * HOUT];
        outp[(c * N_NODES + row) * HOUT + lane] = a;
    }
}

extern "C" void kernel_launch(void* const* d_in, const int* in_sizes, int n_in,
                              void* d_out, int out_size, void* d_ws, size_t ws_size,
                              hipStream_t stream) {
    const int*   ei  = (const int*)d_in[0];
    const float* ew  = (const float*)d_in[1];
    const float* X   = (const float*)d_in[2];
    const float* Ws1 = (const float*)d_in[3];
    const float* cw1 = (const float*)d_in[4];
    const float* lw1 = (const float*)d_in[5];
    const float* lb1 = (const float*)d_in[6];
    const float* Ws2 = (const float*)d_in[7];
    const float* cw2 = (const float*)d_in[8];
    const float* lw2 = (const float*)d_in[9];
    const float* lb2 = (const float*)d_in[10];
    float* out = (float*)d_out;

    char* ws = (char*)d_ws;
    size_t off = 0;
    auto alloc = [&](size_t bytes) -> void* {
        void* p = ws + off;
        off += (bytes + 255) & ~size_t(255);
        return p;
    };
    int*   counts    = (int*)alloc(N_NODES * 4);
    int*   row_start = (int*)alloc((N_NODES + 1) * 4);
    int*   cursor    = (int*)alloc(N_NODES * 4);
    uint2* edges     = (uint2*)alloc((size_t)NE_TOT * 8);
    float* H0a       = (float*)alloc((size_t)C_CH * N_NODES * HOUT * 4);
    float* Ha        = (float*)alloc((size_t)C_CH * N_NODES * HOUT * 4);
    float* H0b       = (float*)alloc((size_t)C_CH * N_NODES * HOUT * 4);

    hipMemsetAsync(counts, 0, N_NODES * 4, stream);

    count_kernel  <<<NE_TOT / 256, 256, 0, stream>>>(ei, counts);
    scan_kernel   <<<1, 1024, 0, stream>>>(counts, row_start, cursor);
    scatter_kernel<<<NE_TOT / 256, 256, 0, stream>>>(ei, ew, cursor, edges);

    // FastGTN #1
    init_kernel<<<(C_CH * N_NODES * HOUT) / 256, 256, 0, stream>>>(X, Ws1, H0a);
    spmm_kernel<<<N_NODES / 2, 256, 0, stream>>>(row_start, edges, H0a, Ha, cw1);
    fused_tail_kernel<false><<<N_NODES, 128, 0, stream>>>(
        row_start, edges, Ha, H0a, cw1, lw1, lb1, Ws2, H0b);

    // FastGTN #2
    spmm_kernel<<<N_NODES / 2, 256, 0, stream>>>(row_start, edges, H0b, Ha, cw2);
    fused_tail_kernel<true><<<N_NODES, 128, 0, stream>>>(
        row_start, edges, Ha, H0b, cw2, lw2, lb2, nullptr, out);
}

// Round 3
// 197.775 us; speedup vs baseline: 2.0226x; 1.0136x over previous
//
#include <hip/hip_runtime.h>

#define T_REL   4
#define E_EDGES 131072
#define N_NODES 4096
#define C_CH    2
#define HOUT    64
#define NE_TOT  (T_REL * E_EDGES)

// ---------------------------------------------------------------- CSR build
__global__ void zero_kernel(int* __restrict__ counts) {
    counts[blockIdx.x * 256 + threadIdx.x] = 0;
}

__global__ void count_kernel(const int* __restrict__ ei, int* __restrict__ counts) {
    int idx = blockIdx.x * blockDim.x + threadIdx.x;
    int t = idx >> 17;              // E = 2^17
    int e = idx & (E_EDGES - 1);
    int src = ei[(t * 2 + 0) * E_EDGES + e];
    atomicAdd(&counts[src], 1);
}

__global__ void scan_kernel(const int* __restrict__ counts,
                            int* __restrict__ row_start,
                            int* __restrict__ cursor) {
    __shared__ int sdata[1024];
    int tid = threadIdx.x;          // 1024 threads, 4 elements each
    int base = tid * 4;
    int v[4];
    int s = 0;
#pragma unroll
    for (int j = 0; j < 4; ++j) { v[j] = counts[base + j]; s += v[j]; }
    sdata[tid] = s;
    __syncthreads();
    for (int off = 1; off < 1024; off <<= 1) {
        int x = sdata[tid] + ((tid >= off) ? sdata[tid - off] : 0);
        __syncthreads();
        sdata[tid] = x;
        __syncthreads();
    }
    int run = sdata[tid] - s;       // exclusive prefix
#pragma unroll
    for (int j = 0; j < 4; ++j) {
        row_start[base + j] = run;
        cursor[base + j]    = run;
        run += v[j];
    }
    if (tid == 1023) row_start[4096] = run;
}

__global__ void scatter_kernel(const int* __restrict__ ei,
                               const float* __restrict__ ew,
                               int* __restrict__ cursor,
                               uint2* __restrict__ edges) {
    int idx = blockIdx.x * blockDim.x + threadIdx.x;
    int t = idx >> 17;
    int e = idx & (E_EDGES - 1);
    int src = ei[(t * 2 + 0) * E_EDGES + e];
    int dst = ei[(t * 2 + 1) * E_EDGES + e];
    float w = ew[t * E_EDGES + e];
    int pos = atomicAdd(&cursor[src], 1);
    edges[pos] = make_uint2((unsigned)dst | ((unsigned)t << 16), __float_as_uint(w));
}

// ------------------------------------------------- H0[c,n,h] = X[n,:] @ Ws1[c,:,h]
__global__ void init_kernel(const float* __restrict__ X,
                            const float* __restrict__ Ws,
                            float* __restrict__ H0) {
    int idx = blockIdx.x * 256 + threadIdx.x;   // c*N*64 + n*64 + h
    int h = idx & 63;
    int n = (idx >> 6) & (N_NODES - 1);
    int c = idx >> 18;
    const float4* xv = (const float4*)(X + n * 128);
    const float*  w  = Ws + c * 128 * HOUT + h;
    float acc = 0.f;
#pragma unroll 8
    for (int k4 = 0; k4 < 32; ++k4) {
        float4 xx = xv[k4];
        acc += xx.x * w[(k4 * 4 + 0) * HOUT];
        acc += xx.y * w[(k4 * 4 + 1) * HOUT];
        acc += xx.z * w[(k4 * 4 + 2) * HOUT];
        acc += xx.w * w[(k4 * 4 + 3) * HOUT];
    }
    H0[idx] = acc;
}

// ---------------------------------------------------------------- helpers
__device__ __forceinline__ void softmax4(const float* __restrict__ conv_w,
                                         int layer, int c, float f[4]) {
#pragma unroll
    for (int t = 0; t < 4; ++t) f[t] = conv_w[(layer * C_CH + c) * T_REL + t];
    float m = fmaxf(fmaxf(f[0], f[1]), fmaxf(f[2], f[3]));
    float s = 0.f;
#pragma unroll
    for (int t = 0; t < 4; ++t) { f[t] = expf(f[t] - m); s += f[t]; }
    float inv = 1.0f / s;
#pragma unroll
    for (int t = 0; t < 4; ++t) f[t] *= inv;
}

__device__ __forceinline__ float selw(const float f[4], int t) {
    float a = (t & 1) ? f[1] : f[0];
    float b = (t & 1) ? f[3] : f[2];
    return (t & 2) ? b : a;
}

// wave-level SpMM for one (row, channel): 4 edges per step (one per 16-lane
// group), each lane gathers a float4 quarter-row; 4x unrolled (16 edges in
// flight); shfl reduce at the end.
__device__ __forceinline__ float4 spmm_row(const int* __restrict__ row_start,
                                           const uint2* __restrict__ edges,
                                           const float* __restrict__ Hc,
                                           const float f[4], int row, int lane) {
    int g  = lane >> 4;    // which edge of the group of 4
    int hq = lane & 15;    // float4 slot within the 64-wide row
    int e0 = row_start[row], e1 = row_start[row + 1];
    float4 acc = make_float4(0.f, 0.f, 0.f, 0.f);
    int e = e0;
    for (; e + 16 <= e1; e += 16) {
        uint2 r0 = edges[e + g];
        uint2 r1 = edges[e + 4 + g];
        uint2 r2 = edges[e + 8 + g];
        uint2 r3 = edges[e + 12 + g];
        float w0 = __uint_as_float(r0.y) * selw(f, (int)(r0.x >> 16));
        float w1 = __uint_as_float(r1.y) * selw(f, (int)(r1.x >> 16));
        float w2 = __uint_as_float(r2.y) * selw(f, (int)(r2.x >> 16));
        float w3 = __uint_as_float(r3.y) * selw(f, (int)(r3.x >> 16));
        float4 v0 = ((const float4*)(Hc + (r0.x & 0xFFFF) * HOUT))[hq];
        float4 v1 = ((const float4*)(Hc + (r1.x & 0xFFFF) * HOUT))[hq];
        float4 v2 = ((const float4*)(Hc + (r2.x & 0xFFFF) * HOUT))[hq];
        float4 v3 = ((const float4*)(Hc + (r3.x & 0xFFFF) * HOUT))[hq];
        acc.x += w0 * v0.x; acc.y += w0 * v0.y; acc.z += w0 * v0.z; acc.w += w0 * v0.w;
        acc.x += w1 * v1.x; acc.y += w1 * v1.y; acc.z += w1 * v1.z; acc.w += w1 * v1.w;
        acc.x += w2 * v2.x; acc.y += w2 * v2.y; acc.z += w2 * v2.z; acc.w += w2 * v2.w;
        acc.x += w3 * v3.x; acc.y += w3 * v3.y; acc.z += w3 * v3.z; acc.w += w3 * v3.w;
    }
    for (; e + 4 <= e1; e += 4) {
        uint2 r0 = edges[e + g];
        float w0 = __uint_as_float(r0.y) * selw(f, (int)(r0.x >> 16));
        float4 v0 = ((const float4*)(Hc + (r0.x & 0xFFFF) * HOUT))[hq];
        acc.x += w0 * v0.x; acc.y += w0 * v0.y; acc.z += w0 * v0.z; acc.w += w0 * v0.w;
    }
    int rem = e1 - e;
    if (g < rem) {
        uint2 r0 = edges[e + g];
        float w0 = __uint_as_float(r0.y) * selw(f, (int)(r0.x >> 16));
        float4 v0 = ((const float4*)(Hc + (r0.x & 0xFFFF) * HOUT))[hq];
        acc.x += w0 * v0.x; acc.y += w0 * v0.y; acc.z += w0 * v0.z; acc.w += w0 * v0.w;
    }
    // combine the 4 edge-groups: after xor16+xor32 every lane has the full sum
    acc.x += __shfl_xor(acc.x, 16); acc.y += __shfl_xor(acc.y, 16);
    acc.z += __shfl_xor(acc.z, 16); acc.w += __shfl_xor(acc.w, 16);
    acc.x += __shfl_xor(acc.x, 32); acc.y += __shfl_xor(acc.y, 32);
    acc.z += __shfl_xor(acc.z, 32); acc.w += __shfl_xor(acc.w, 32);
    return acc;
}

// ---------------------------------------------------------------- layer-0 SpMM
__global__ void spmm_kernel(const int* __restrict__ row_start,
                            const uint2* __restrict__ edges,
                            const float* __restrict__ Hin,
                            float* __restrict__ Hout,
                            const float* __restrict__ conv_w) {
    int wid  = threadIdx.x >> 6;              // 4 waves: 2 rows x 2 channels
    int lane = threadIdx.x & 63;
    int row  = blockIdx.x * 2 + (wid >> 1);
    int c    = wid & 1;
    float f[4]; softmax4(conv_w, 0, c, f);
    const float* Hc = Hin + c * (N_NODES * HOUT);
    float4 acc = spmm_row(row_start, edges, Hc, f, row, lane);
    if (lane < 16)
        ((float4*)(Hout + (c * N_NODES + row) * HOUT))[lane] = acc;
}

// ------------- layer-1 SpMM + beta-combine + linear (+ next-FastGTN init)
template <bool FINAL>
__global__ void fused_tail_kernel(const int* __restrict__ row_start,
                                  const uint2* __restrict__ edges,
                                  const float* __restrict__ Hin,   // layer-1 result
                                  const float* __restrict__ H0,    // X_ (detached init)
                                  const float* __restrict__ conv_w,
                                  const float* __restrict__ lin_w,
                                  const float* __restrict__ lin_b,
                                  const float* __restrict__ Ws_next,
                                  float* __restrict__ outp) {
    __shared__ float h2s[C_CH * HOUT];
    __shared__ float hcomb[C_CH * HOUT];
    __shared__ float mids[HOUT];
    int tid  = threadIdx.x;        // 128 = 2 waves, wave == channel
    int c    = tid >> 6;
    int lane = tid & 63;
    int row  = blockIdx.x;

    float f[4]; softmax4(conv_w, 1, c, f);
    const float* Hc = Hin + c * (N_NODES * HOUT);
    float4 acc = spmm_row(row_start, edges, Hc, f, row, lane);
    if (lane < 16) ((float4*)(h2s + c * HOUT))[lane] = acc;
    __syncthreads();

    // H_ = relu(0.1*X_ + 0.9*H2), laid out j = c*64 + h
    {
        float h0v = H0[(c * N_NODES + row) * HOUT + lane];
        hcomb[tid] = fmaxf(0.1f * h0v + 0.9f * h2s[tid], 0.f);
    }
    __syncthreads();

    if (FINAL) {
        if (tid < 64) {
            float a = lin_b[tid];
#pragma unroll 8
            for (int j = 0; j < C_CH * HOUT; ++j) a += hcomb[j] * lin_w[j * HOUT + tid];
            outp[row * HOUT + tid] = fmaxf(a, 0.f);
        }
    } else {
        if (tid < 64) {
            float a = lin_b[tid];
#pragma unroll 8
            for (int j = 0; j < C_CH * HOUT; ++j) a += hcomb[j] * lin_w[j * HOUT + tid];
            mids[tid] = fmaxf(a, 0.f);
        }
        __syncthreads();
        // next FastGTN init: H0'[c,row,h] = sum_k mid[k] * Ws_next[c,k,h]
        float a = 0.f;
        const float* w = Ws_next + c * HOUT * HOUT + lane;
#pragma unroll 8
        for (int k = 0; k < HOUT; ++k) a += mids[k] * w[k * HOUT];
        outp[(c * N_NODES + row) * HOUT + lane] = a;
    }
}

extern "C" void kernel_launch(void* const* d_in, const int* in_sizes, int n_in,
                              void* d_out, int out_size, void* d_ws, size_t ws_size,
                              hipStream_t stream) {
    const int*   ei  = (const int*)d_in[0];
    const float* ew  = (const float*)d_in[1];
    const float* X   = (const float*)d_in[2];
    const float* Ws1 = (const float*)d_in[3];
    const float* cw1 = (const float*)d_in[4];
    const float* lw1 = (const float*)d_in[5];
    const float* lb1 = (const float*)d_in[6];
    const float* Ws2 = (const float*)d_in[7];
    const float* cw2 = (const float*)d_in[8];
    const float* lw2 = (const float*)d_in[9];
    const float* lb2 = (const float*)d_in[10];
    float* out = (float*)d_out;

    char* ws = (char*)d_ws;
    size_t off = 0;
    auto alloc = [&](size_t bytes) -> void* {
        void* p = ws + off;
        off += (bytes + 255) & ~size_t(255);
        return p;
    };
    int*   counts    = (int*)alloc(N_NODES * 4);
    int*   row_start = (int*)alloc((N_NODES + 1) * 4);
    int*   cursor    = (int*)alloc(N_NODES * 4);
    uint2* edges     = (uint2*)alloc((size_t)NE_TOT * 8);
    float* H0a       = (float*)alloc((size_t)C_CH * N_NODES * HOUT * 4);
    float* Ha        = (float*)alloc((size_t)C_CH * N_NODES * HOUT * 4);
    float* H0b       = (float*)alloc((size_t)C_CH * N_NODES * HOUT * 4);

    zero_kernel   <<<N_NODES / 256, 256, 0, stream>>>(counts);
    count_kernel  <<<NE_TOT / 256, 256, 0, stream>>>(ei, counts);
    scan_kernel   <<<1, 1024, 0, stream>>>(counts, row_start, cursor);
    scatter_kernel<<<NE_TOT / 256, 256, 0, stream>>>(ei, ew, cursor, edges);

    // FastGTN #1
    init_kernel<<<(C_CH * N_NODES * HOUT) / 256, 256, 0, stream>>>(X, Ws1, H0a);
    spmm_kernel<<<N_NODES / 2, 256, 0, stream>>>(row_start, edges, H0a, Ha, cw1);
    fused_tail_kernel<false><<<N_NODES, 128, 0, stream>>>(
        row_start, edges, Ha, H0a, cw1, lw1, lb1, Ws2, H0b);

    // FastGTN #2
    spmm_kernel<<<N_NODES / 2, 256, 0, stream>>>(row_start, edges, H0b, Ha, cw2);
    fused_tail_kernel<true><<<N_NODES, 128, 0, stream>>>(
        row_start, edges, Ha, H0b, cw2, lw2, lb2, nullptr, out);
}